// Round 1
// baseline (2599.785 us; speedup 1.0000x reference)
//
#include <hip/hip_runtime.h>
#include <hip/hip_bf16.h>

#define BB 8
#define CC 256
#define NHD 8
#define DD 128
#define NN 1024      // H*W = 32*32
#define DIM 1024     // 4*CC
#define H3 3072      // qkv rows
#define MM 8192      // B*N

__constant__ int   d_IDX[16] = {0,1,2,3, 1,0,3,2, 2,3,0,1, 3,2,1,0};
__constant__ float d_SGN[16] = {1.f,-1.f,-1.f,-1.f, 1.f,1.f,1.f,-1.f,
                                1.f,-1.f,1.f,1.f,  1.f,1.f,-1.f,1.f};

// ---------------------------------------------------------------------------
// Kernel 1: build effective (transposed) weight matrices
//   weffT_qkv [col(p,c)][row(q,o)]  : (1024 x 3072)
//   weffT_proj[col(p,c)][row(q,o)]  : (1024 x 1024)
// ---------------------------------------------------------------------------
__global__ __launch_bounds__(256) void build_weff(
    const float* __restrict__ wqkv, const float* __restrict__ wproj,
    float* __restrict__ weffT_qkv, float* __restrict__ weffT_proj) {
  int tid = blockIdx.x * blockDim.x + threadIdx.x;
  int stride = gridDim.x * blockDim.x;
  const int total1 = DIM * H3;
  for (int i = tid; i < total1; i += stride) {
    int col = i / H3, row = i - col * H3;
    int p = col >> 8, c = col & 255;
    int q = row / 768, o = row - q * 768;
    int idx = d_IDX[q * 4 + p];
    float s = d_SGN[q * 4 + p];
    weffT_qkv[i] = s * wqkv[(idx * 768 + o) * 256 + c];
  }
  const int total2 = DIM * DIM;
  for (int i = tid; i < total2; i += stride) {
    int col = i >> 10, row = i & 1023;
    int p = col >> 8, c = col & 255;
    int q = row >> 8, o = row & 255;
    int idx = d_IDX[q * 4 + p];
    float s = d_SGN[q * 4 + p];
    weffT_proj[i] = s * wproj[(idx * 256 + o) * 256 + c];
  }
}

// ---------------------------------------------------------------------------
// Kernel 2: QKV GEMM. A = gathered x (M=8192 x K=1024), B = weffT (1024x3072)
// Output scattered into Q/K/V buffers with layout (B, heads, N, d).
// Tile: 64(bn) x 64(row), 256 threads, 4x4 microtile, K-chunk 16.
// ---------------------------------------------------------------------------
__global__ __launch_bounds__(256) void gemm_qkv(
    const float* __restrict__ x, const float* __restrict__ weffT,
    const float* __restrict__ bqkv,
    float* __restrict__ Qb, float* __restrict__ Kb, float* __restrict__ Vb) {
  int bn0 = blockIdx.x * 64;
  int row0 = blockIdx.y * 64;
  int b = bn0 >> 10;
  int n0 = bn0 & 1023;
  int tid = threadIdx.x;
  __shared__ float As[16][66];
  __shared__ float Bs[16][66];
  float acc[4][4];
#pragma unroll
  for (int i = 0; i < 4; ++i)
#pragma unroll
    for (int j = 0; j < 4; ++j) acc[i][j] = 0.f;

  int tx = tid & 15, ty = tid >> 4;
  int l64 = tid & 63, klb = tid >> 6;

  for (int k0 = 0; k0 < DIM; k0 += 16) {
#pragma unroll
    for (int kk = klb; kk < 16; kk += 4) {
      int col = k0 + kk;
      int p = col >> 8, c = col & 255;
      As[kk][l64] = x[(((size_t)b * 256 + c) * 4 + p) * 1024 + n0 + l64];
    }
#pragma unroll
    for (int kk = klb; kk < 16; kk += 4) {
      Bs[kk][l64] = weffT[(size_t)(k0 + kk) * H3 + row0 + l64];
    }
    __syncthreads();
#pragma unroll
    for (int k = 0; k < 16; ++k) {
      float a[4], w[4];
#pragma unroll
      for (int i = 0; i < 4; ++i) a[i] = As[k][ty * 4 + i];
#pragma unroll
      for (int j = 0; j < 4; ++j) w[j] = Bs[k][tx * 4 + j];
#pragma unroll
      for (int i = 0; i < 4; ++i)
#pragma unroll
        for (int j = 0; j < 4; ++j) acc[i][j] += a[i] * w[j];
    }
    __syncthreads();
  }
  // epilogue: bias + scatter into Q/K/V (B, h, N, d)
#pragma unroll
  for (int j = 0; j < 4; ++j) {
    int row = row0 + tx * 4 + j;
    int q = row / 768, o = row - q * 768;
    int sel = o >> 8, oc = o & 255;
    int ch = q * 256 + oc;
    int head = ch >> 7, dim = ch & 127;
    float bias = bqkv[row];
    float* dst = (sel == 0) ? Qb : (sel == 1 ? Kb : Vb);
    size_t base = (size_t)(b * NHD + head) * NN * DD + dim;
#pragma unroll
    for (int i = 0; i < 4; ++i) {
      int n = n0 + ty * 4 + i;
      dst[base + (size_t)n * DD] = acc[i][j] + bias;
    }
  }
}

// ---------------------------------------------------------------------------
// Kernel 3: attention. Block = one (b,head) x 8-query tile, 256 threads.
// Full score rows (8x1024) in LDS, block softmax, PV with coalesced V rows.
// ---------------------------------------------------------------------------
#define QT 8
__global__ __launch_bounds__(256) void attn_kernel(
    const float* __restrict__ Qb, const float* __restrict__ Kb,
    const float* __restrict__ Vb, float* __restrict__ AO) {
  int blk = blockIdx.x;            // bh*(NN/QT) + nt
  int nt = blk & (NN / QT - 1);
  int bh = blk >> 7;
  int n0 = nt * QT;
  const float* Q = Qb + ((size_t)bh * NN + n0) * DD;
  const float* K = Kb + (size_t)bh * NN * DD;
  const float* V = Vb + (size_t)bh * NN * DD;

  __shared__ float qs[QT][DD];
  __shared__ float sc[QT][NN];
  __shared__ float rowsum[QT];

  int tid = threadIdx.x;
  for (int i = tid; i < QT * DD; i += 256) ((float*)qs)[i] = Q[i];
  __syncthreads();

  const float scale = 0.08838834764831845f;  // 128^-0.5

  // ---- QK^T: each thread owns rows m = tid + r*256, r=0..3 ----
  {
    float acc[QT][4];
#pragma unroll
    for (int qi = 0; qi < QT; ++qi)
#pragma unroll
      for (int r = 0; r < 4; ++r) acc[qi][r] = 0.f;
    for (int d = 0; d < DD; d += 4) {
      float4 kv[4];
#pragma unroll
      for (int r = 0; r < 4; ++r)
        kv[r] = *(const float4*)(K + (size_t)(tid + r * 256) * DD + d);
#pragma unroll
      for (int qi = 0; qi < QT; ++qi) {
        float4 qv = *(const float4*)(&qs[qi][d]);
#pragma unroll
        for (int r = 0; r < 4; ++r)
          acc[qi][r] += qv.x * kv[r].x + qv.y * kv[r].y +
                        qv.z * kv[r].z + qv.w * kv[r].w;
      }
    }
#pragma unroll
    for (int qi = 0; qi < QT; ++qi)
#pragma unroll
      for (int r = 0; r < 4; ++r) sc[qi][tid + r * 256] = acc[qi][r] * scale;
  }
  __syncthreads();

  // ---- softmax: group g (32 lanes) handles row g ----
  {
    int g = tid >> 5;
    int lane = tid & 31;
    float mx = -1e30f;
    for (int m = lane; m < NN; m += 32) mx = fmaxf(mx, sc[g][m]);
#pragma unroll
    for (int off = 16; off > 0; off >>= 1)
      mx = fmaxf(mx, __shfl_down(mx, off, 32));
    mx = __shfl(mx, 0, 32);
    float s = 0.f;
    for (int m = lane; m < NN; m += 32) {
      float e = __expf(sc[g][m] - mx);
      sc[g][m] = e;
      s += e;
    }
#pragma unroll
    for (int off = 16; off > 0; off >>= 1) s += __shfl_down(s, off, 32);
    if (lane == 0) rowsum[g] = s;
  }
  __syncthreads();

  // ---- PV: thread = (qg, d); qg in {0,1} handles qi = qg*4+j ----
  {
    int d = tid & 127;
    int qg = tid >> 7;
    float po[4] = {0.f, 0.f, 0.f, 0.f};
    for (int m = 0; m < NN; m += 4) {
      float vv[4];
#pragma unroll
      for (int t = 0; t < 4; ++t) vv[t] = V[(size_t)(m + t) * DD + d];
#pragma unroll
      for (int j = 0; j < 4; ++j) {
        float4 s = *(const float4*)(&sc[qg * 4 + j][m]);
        po[j] += s.x * vv[0] + s.y * vv[1] + s.z * vv[2] + s.w * vv[3];
      }
    }
#pragma unroll
    for (int j = 0; j < 4; ++j) {
      int qi = qg * 4 + j;
      float inv = 1.0f / rowsum[qi];
      AO[((size_t)bh * NN + n0 + qi) * DD + d] = po[j] * inv;
    }
  }
}

// ---------------------------------------------------------------------------
// Kernel 4: quaternion depthwise 3x3 conv + b_pe, written (transposed) into
// the final output buffer. Block = one (b, co), computes all 4 q outputs.
// ---------------------------------------------------------------------------
__global__ __launch_bounds__(256) void qdwconv_kernel(
    const float* __restrict__ x, const float* __restrict__ wpe,
    const float* __restrict__ bpe, float* __restrict__ out) {
  int blk = blockIdx.x;
  int co = blk & 255;
  int b = blk >> 8;
  __shared__ float pl[4][34 * 34];
  __shared__ float wsm[4][9];
  int tid = threadIdx.x;
  for (int i = tid; i < 4 * 34 * 34; i += 256) ((float*)pl)[i] = 0.f;
  if (tid < 36) wsm[tid / 9][tid % 9] = wpe[((tid / 9) * 256 + co) * 9 + tid % 9];
  __syncthreads();
  for (int i = tid; i < 4 * 1024; i += 256) {
    int p = i >> 10, n = i & 1023;
    int h = n >> 5, w = n & 31;
    pl[p][(h + 1) * 34 + (w + 1)] =
        x[(((size_t)b * 256 + co) * 4 + p) * 1024 + n];
  }
  __syncthreads();
  for (int n = tid; n < 1024; n += 256) {
    int h = n >> 5, w = n & 31;
    float in[4][9];
#pragma unroll
    for (int p = 0; p < 4; ++p)
#pragma unroll
      for (int t = 0; t < 9; ++t)
        in[p][t] = pl[p][(h + t / 3) * 34 + (w + t % 3)];
#pragma unroll
    for (int q = 0; q < 4; ++q) {
      float acc = bpe[q * 256 + co];
#pragma unroll
      for (int p = 0; p < 4; ++p) {
        int idx = d_IDX[q * 4 + p];
        float s = d_SGN[q * 4 + p];
        float sub = 0.f;
#pragma unroll
        for (int t = 0; t < 9; ++t) sub += in[p][t] * wsm[idx][t];
        acc += s * sub;
      }
      // out layout: (B, Cc, 4, H, W)
      out[(((size_t)b * 256 + co) * 4 + q) * 1024 + n] = acc;
    }
  }
}

// ---------------------------------------------------------------------------
// Kernel 5: proj GEMM. A = attn out gathered (8192 x 1024), B = weffT_proj.
// Epilogue: += into out (dwconv term already there), + bias, transposed store.
// ---------------------------------------------------------------------------
__global__ __launch_bounds__(256) void gemm_proj(
    const float* __restrict__ AO, const float* __restrict__ weffT,
    const float* __restrict__ bproj, float* __restrict__ out) {
  int bn0 = blockIdx.x * 64;
  int row0 = blockIdx.y * 64;
  int b = bn0 >> 10;
  int n0 = bn0 & 1023;
  int tid = threadIdx.x;
  __shared__ float As[16][66];
  __shared__ float Bs[16][66];
  float acc[4][4];
#pragma unroll
  for (int i = 0; i < 4; ++i)
#pragma unroll
    for (int j = 0; j < 4; ++j) acc[i][j] = 0.f;

  int tx = tid & 15, ty = tid >> 4;
  int l64 = tid & 63, klb = tid >> 6;
  int kl = tid & 15;

  for (int k0 = 0; k0 < DIM; k0 += 16) {
    // A tile: col-fastest mapping so AO reads are contiguous in d
    {
      int col = k0 + kl;
      int head = col >> 7, dcol = col & 127;
      const float* src = AO + ((size_t)(b * NHD + head) * NN + n0) * DD + dcol;
#pragma unroll
      for (int bnl = tid >> 4; bnl < 64; bnl += 16)
        As[kl][bnl] = src[(size_t)bnl * DD];
    }
#pragma unroll
    for (int kk = klb; kk < 16; kk += 4)
      Bs[kk][l64] = weffT[(size_t)(k0 + kk) * DIM + row0 + l64];
    __syncthreads();
#pragma unroll
    for (int k = 0; k < 16; ++k) {
      float a[4], w[4];
#pragma unroll
      for (int i = 0; i < 4; ++i) a[i] = As[k][ty * 4 + i];
#pragma unroll
      for (int j = 0; j < 4; ++j) w[j] = Bs[k][tx * 4 + j];
#pragma unroll
      for (int i = 0; i < 4; ++i)
#pragma unroll
        for (int j = 0; j < 4; ++j) acc[i][j] += a[i] * w[j];
    }
    __syncthreads();
  }
#pragma unroll
  for (int j = 0; j < 4; ++j) {
    int row = row0 + tx * 4 + j;
    int q = row >> 8, o = row & 255;
    float bias = bproj[row];
#pragma unroll
    for (int i = 0; i < 4; ++i) {
      int n = n0 + ty * 4 + i;
      size_t oidx = (((size_t)b * 256 + o) * 4 + q) * 1024 + n;
      out[oidx] += acc[i][j] + bias;
    }
  }
}

// ---------------------------------------------------------------------------
extern "C" void kernel_launch(void* const* d_in, const int* in_sizes, int n_in,
                              void* d_out, int out_size, void* d_ws,
                              size_t ws_size, hipStream_t stream) {
  const float* x      = (const float*)d_in[0];
  const float* w_qkv  = (const float*)d_in[1];
  const float* b_qkv  = (const float*)d_in[2];
  const float* w_proj = (const float*)d_in[3];
  const float* b_proj = (const float*)d_in[4];
  const float* w_pe   = (const float*)d_in[5];
  const float* b_pe   = (const float*)d_in[6];
  float* out = (float*)d_out;

  float* ws = (float*)d_ws;
  float* weffT_qkv  = ws;                                  // 1024*3072
  float* weffT_proj = weffT_qkv + (size_t)DIM * H3;        // 1024*1024
  float* Qb = weffT_proj + (size_t)DIM * DIM;              // 8*8*1024*128
  float* Kb = Qb + (size_t)BB * NHD * NN * DD;
  float* Vb = Kb + (size_t)BB * NHD * NN * DD;
  float* AO = Vb + (size_t)BB * NHD * NN * DD;
  // total: ~37.7M floats = 151 MB

  hipLaunchKernelGGL(build_weff, dim3(2048), dim3(256), 0, stream,
                     w_qkv, w_proj, weffT_qkv, weffT_proj);
  hipLaunchKernelGGL(gemm_qkv, dim3(MM / 64, H3 / 64), dim3(256), 0, stream,
                     x, weffT_qkv, b_qkv, Qb, Kb, Vb);
  hipLaunchKernelGGL(attn_kernel, dim3(BB * NHD * (NN / QT)), dim3(256), 0,
                     stream, Qb, Kb, Vb, AO);
  hipLaunchKernelGGL(qdwconv_kernel, dim3(BB * CC), dim3(256), 0, stream,
                     x, w_pe, b_pe, out);
  hipLaunchKernelGGL(gemm_proj, dim3(MM / 64, DIM / 64), dim3(256), 0, stream,
                     AO, weffT_proj, b_proj, out);
}

// Round 2
// 385.012 us; speedup vs baseline: 6.7525x; 6.7525x over previous
//
#include <hip/hip_runtime.h>
#include <hip/hip_bf16.h>

typedef unsigned short u16;
typedef float f32x4 __attribute__((ext_vector_type(4)));
typedef __bf16 bf16x8 __attribute__((ext_vector_type(8)));
typedef unsigned short su8v __attribute__((ext_vector_type(8)));

#define BB 8
#define NHD 8
#define DD 128
#define NN 1024
#define DIM 1024
#define H3 3072
#define MM 8192

__constant__ int   d_IDX[16] = {0,1,2,3, 1,0,3,2, 2,3,0,1, 3,2,1,0};
__constant__ float d_SGN[16] = {1.f,-1.f,-1.f,-1.f, 1.f,1.f,1.f,-1.f,
                                1.f,-1.f,1.f,1.f,  1.f,1.f,-1.f,1.f};

__device__ __forceinline__ f32x4 mfma16(su8v a, su8v b, f32x4 c) {
  return __builtin_amdgcn_mfma_f32_16x16x32_bf16(
      __builtin_bit_cast(bf16x8, a), __builtin_bit_cast(bf16x8, b), c, 0, 0, 0);
}
__device__ __forceinline__ u16 f2b(float f) {
  unsigned int u = __builtin_bit_cast(unsigned int, f);
  u += 0x7fffu + ((u >> 16) & 1u);
  return (u16)(u >> 16);
}

// ---------------------------------------------------------------------------
// prep_weff: effective weights, row-major [out_row][in_col] (= B^T layout), bf16
// ---------------------------------------------------------------------------
__global__ __launch_bounds__(256) void prep_weff(
    const float* __restrict__ wqkv, const float* __restrict__ wproj,
    u16* __restrict__ weffQ, u16* __restrict__ weffP) {
  int tid = blockIdx.x * 256 + threadIdx.x;
  int stride = gridDim.x * 256;
  for (int i = tid; i < H3 * DIM; i += stride) {
    int row = i >> 10, col = i & 1023;
    int q = row / 768, o = row - q * 768;
    int p = col >> 8, c = col & 255;
    weffQ[i] = f2b(d_SGN[q * 4 + p] * wqkv[(d_IDX[q * 4 + p] * 768 + o) * 256 + c]);
  }
  for (int i = tid; i < DIM * DIM; i += stride) {
    int row = i >> 10, col = i & 1023;
    int q = row >> 8, o = row & 255;
    int p = col >> 8, c = col & 255;
    weffP[i] = f2b(d_SGN[q * 4 + p] * wproj[(d_IDX[q * 4 + p] * 256 + o) * 256 + c]);
  }
}

// ---------------------------------------------------------------------------
// prep_x: x (B,Cc,4,N) fp32 -> Ax bf16 [8192 (b,n)][1024 (p,c)]
// ---------------------------------------------------------------------------
__global__ __launch_bounds__(256) void prep_x(
    const float* __restrict__ x, u16* __restrict__ Ax) {
  int id = blockIdx.x * 256 + threadIdx.x;  // float4 chunk id, exact cover
  const float4* xv = (const float4*)x;
  float4 f = xv[id];
  int n4 = id & 255;
  int rem = id >> 8;
  int p = rem & 3, c = (rem >> 2) & 255, b = rem >> 10;
  int col = p * 256 + c;
  size_t rbase = (size_t)(b * 1024 + n4 * 4) * 1024 + col;
  Ax[rbase] = f2b(f.x);
  Ax[rbase + 1024] = f2b(f.y);
  Ax[rbase + 2048] = f2b(f.z);
  Ax[rbase + 3072] = f2b(f.w);
}

// ---------------------------------------------------------------------------
// Shared bf16 MFMA GEMM core: C(128x128) tile, K=1024, BK=32.
// Ag: rows m (k-contiguous, ld=1024); Bg: rows n (k-contiguous, ld=1024).
// ---------------------------------------------------------------------------
#define LDK 40  // padded LDS row stride (elems): 80B rows, 16B-aligned, 2-way banks
__device__ __forceinline__ void gemm_core(
    const u16* __restrict__ Ag, const u16* __restrict__ Bg,
    u16* As, u16* Bs, int tid, f32x4 acc[4][4]) {
  int w = tid >> 6, lane = tid & 63, l16 = lane & 15, quad = lane >> 4;
  int mt = (w & 1) * 64, nt = (w >> 1) * 64;
  for (int k0 = 0; k0 < 1024; k0 += 32) {
    __syncthreads();
#pragma unroll
    for (int t = 0; t < 2; ++t) {
      int e = tid * 16 + t * 8;
      int row = e >> 5, col = e & 31;
      su8v va = *(const su8v*)(Ag + (size_t)row * 1024 + k0 + col);
      su8v vb = *(const su8v*)(Bg + (size_t)row * 1024 + k0 + col);
      *(su8v*)(As + row * LDK + col) = va;
      *(su8v*)(Bs + row * LDK + col) = vb;
    }
    __syncthreads();
    su8v af[4], bf[4];
#pragma unroll
    for (int i = 0; i < 4; ++i)
      af[i] = *(const su8v*)(As + (mt + i * 16 + l16) * LDK + quad * 8);
#pragma unroll
    for (int j = 0; j < 4; ++j)
      bf[j] = *(const su8v*)(Bs + (nt + j * 16 + l16) * LDK + quad * 8);
#pragma unroll
    for (int i = 0; i < 4; ++i)
#pragma unroll
      for (int j = 0; j < 4; ++j)
        acc[i][j] = mfma16(af[i], bf[j], acc[i][j]);
  }
}

// ---------------------------------------------------------------------------
// QKV GEMM: A=Ax [8192][1024], B^T=weffQ [3072][1024]; scatter bf16 Q/K/V (b,h,n,d)
// ---------------------------------------------------------------------------
__global__ __launch_bounds__(256) void gemm_qkv_mfma(
    const u16* __restrict__ Ax, const u16* __restrict__ weffQ,
    const float* __restrict__ bqkv,
    u16* __restrict__ Qb, u16* __restrict__ Kb, u16* __restrict__ Vb) {
  __shared__ u16 As[128 * LDK];
  __shared__ u16 Bs[128 * LDK];
  int m0 = blockIdx.x * 128, n0 = blockIdx.y * 128;
  int tid = threadIdx.x;
  f32x4 acc[4][4];
#pragma unroll
  for (int i = 0; i < 4; ++i)
#pragma unroll
    for (int j = 0; j < 4; ++j) acc[i][j] = (f32x4){0.f, 0.f, 0.f, 0.f};
  gemm_core(Ax + (size_t)m0 * 1024, weffQ + (size_t)n0 * 1024, As, Bs, tid, acc);

  int w = tid >> 6, lane = tid & 63, l16 = lane & 15, quad = lane >> 4;
  int mt = (w & 1) * 64, nt = (w >> 1) * 64;
#pragma unroll
  for (int j = 0; j < 4; ++j) {
    int n = n0 + nt + j * 16 + l16;
    int q = n / 768, o = n - q * 768;
    int sel = o >> 8, oc = o & 255;
    int ch = q * 256 + oc;
    int head = ch >> 7, d = ch & 127;
    float bias = bqkv[n];
    u16* dst = (sel == 0) ? Qb : (sel == 1 ? Kb : Vb);
#pragma unroll
    for (int i = 0; i < 4; ++i) {
#pragma unroll
      for (int r = 0; r < 4; ++r) {
        int m = m0 + mt + i * 16 + quad * 4 + r;
        int b = m >> 10, npos = m & 1023;
        dst[((size_t)(b * NHD + head) * NN + npos) * DD + d] = f2b(acc[i][j][r] + bias);
      }
    }
  }
}

// ---------------------------------------------------------------------------
// Flash attention, bf16 MFMA. Block = (bh, 64-query tile), 4 waves.
// Writes AO bf16 [8192 (b,n)][1024 (head*128+d)].
// ---------------------------------------------------------------------------
#define ATS 136  // Q/K LDS stride: 272B rows (16B-aligned), 2-way banks
#define VTS 88   // V^T / P stride: 176B rows (16B-aligned), 2-way banks
__global__ __launch_bounds__(256) void attn_mfma(
    const u16* __restrict__ Qb, const u16* __restrict__ Kb,
    const u16* __restrict__ Vb, u16* __restrict__ AO) {
  __shared__ u16 Qs[64 * ATS];
  __shared__ u16 Ks[64 * ATS];
  __shared__ u16 Vt[128 * VTS];
  __shared__ u16 Ps[4 * 16 * VTS];

  int qt = blockIdx.x & 15, bh = blockIdx.x >> 4;
  int n0 = qt * 64;
  const u16* Qg = Qb + ((size_t)bh * NN + n0) * DD;
  const u16* Kg = Kb + (size_t)bh * NN * DD;
  const u16* Vg = Vb + (size_t)bh * NN * DD;

  int tid = threadIdx.x;
  int w = tid >> 6, lane = tid & 63, l16 = lane & 15, quad = lane >> 4;
  u16* Pw = Ps + w * 16 * VTS;

  // stage Q once (visibility covered by first loop barrier)
#pragma unroll
  for (int it = 0; it < 4; ++it) {
    int cid = tid + it * 256;
    int row = cid >> 4, co8 = (cid & 15) * 8;
    *(su8v*)(Qs + row * ATS + co8) = *(const su8v*)(Qg + row * DD + co8);
  }

  const float scale = 0.08838834764831845f;
  float om[4] = {-1e30f, -1e30f, -1e30f, -1e30f};
  float ol[4] = {0.f, 0.f, 0.f, 0.f};
  f32x4 accO[8];
#pragma unroll
  for (int dt = 0; dt < 8; ++dt) accO[dt] = (f32x4){0.f, 0.f, 0.f, 0.f};

  for (int kt = 0; kt < 16; ++kt) {
    int c0 = kt * 64;
    __syncthreads();  // previous tile fully consumed
#pragma unroll
    for (int it = 0; it < 4; ++it) {
      int cid = tid + it * 256;
      int row = cid >> 4, co8 = (cid & 15) * 8;
      *(su8v*)(Ks + row * ATS + co8) = *(const su8v*)(Kg + (size_t)(c0 + row) * DD + co8);
    }
    {
      int key = lane;
#pragma unroll
      for (int it = 0; it < 4; ++it) {
        int d0 = w * 8 + it * 32;
        su8v v = *(const su8v*)(Vg + (size_t)(c0 + key) * DD + d0);
#pragma unroll
        for (int j = 0; j < 8; ++j) Vt[(d0 + j) * VTS + key] = v[j];
      }
    }
    __syncthreads();

    // S = Q K^T (16 queries x 64 keys per wave)
    f32x4 sacc[4];
#pragma unroll
    for (int j = 0; j < 4; ++j) sacc[j] = (f32x4){0.f, 0.f, 0.f, 0.f};
#pragma unroll
    for (int ch = 0; ch < 4; ++ch) {
      su8v a = *(const su8v*)(Qs + (w * 16 + l16) * ATS + ch * 32 + quad * 8);
#pragma unroll
      for (int j = 0; j < 4; ++j) {
        su8v b = *(const su8v*)(Ks + (j * 16 + l16) * ATS + ch * 32 + quad * 8);
        sacc[j] = mfma16(a, b, sacc[j]);
      }
    }

    // online softmax (lane rows r: global query row w*16 + quad*4 + r)
    float mloc[4], alpha[4], ls[4];
#pragma unroll
    for (int r = 0; r < 4; ++r) {
      mloc[r] = fmaxf(fmaxf(sacc[0][r], sacc[1][r]), fmaxf(sacc[2][r], sacc[3][r]));
#pragma unroll
      for (int off = 1; off < 16; off <<= 1)
        mloc[r] = fmaxf(mloc[r], __shfl_xor(mloc[r], off, 16));
      float mnew = fmaxf(om[r], mloc[r] * scale);
      alpha[r] = __expf(om[r] - mnew);
      om[r] = mnew;
      ls[r] = 0.f;
    }
#pragma unroll
    for (int j = 0; j < 4; ++j)
#pragma unroll
      for (int r = 0; r < 4; ++r) {
        float p = __expf(sacc[j][r] * scale - om[r]);
        ls[r] += p;
        Pw[(quad * 4 + r) * VTS + j * 16 + l16] = f2b(p);
      }
#pragma unroll
    for (int r = 0; r < 4; ++r) {
#pragma unroll
      for (int off = 1; off < 16; off <<= 1) ls[r] += __shfl_xor(ls[r], off, 16);
      ol[r] = ol[r] * alpha[r] + ls[r];
    }
#pragma unroll
    for (int dt = 0; dt < 8; ++dt)
#pragma unroll
      for (int r = 0; r < 4; ++r) accO[dt][r] *= alpha[r];

    // O += P V   (P: wave-local LDS round-trip, no barrier needed)
#pragma unroll
    for (int ch = 0; ch < 2; ++ch) {
      su8v ap = *(const su8v*)(Pw + l16 * VTS + ch * 32 + quad * 8);
#pragma unroll
      for (int dt = 0; dt < 8; ++dt) {
        su8v bv = *(const su8v*)(Vt + (dt * 16 + l16) * VTS + ch * 32 + quad * 8);
        accO[dt] = mfma16(ap, bv, accO[dt]);
      }
    }
  }

  // epilogue: normalize, store bf16 to AO[m=b*1024+n][col=head*128+d]
  int b = bh >> 3, head = bh & 7;
#pragma unroll
  for (int r = 0; r < 4; ++r) {
    float inv = 1.0f / ol[r];
    size_t rowbase = (size_t)(b * 1024 + n0 + w * 16 + quad * 4 + r) * 1024 + head * 128;
#pragma unroll
    for (int dt = 0; dt < 8; ++dt)
      AO[rowbase + dt * 16 + l16] = f2b(accO[dt][r] * inv);
  }
}

// ---------------------------------------------------------------------------
// quaternion depthwise 3x3 conv (fp32, unchanged from R1) — writes out
// ---------------------------------------------------------------------------
__global__ __launch_bounds__(256) void qdwconv_kernel(
    const float* __restrict__ x, const float* __restrict__ wpe,
    const float* __restrict__ bpe, float* __restrict__ out) {
  int blk = blockIdx.x;
  int co = blk & 255;
  int b = blk >> 8;
  __shared__ float pl[4][34 * 34];
  __shared__ float wsm[4][9];
  int tid = threadIdx.x;
  for (int i = tid; i < 4 * 34 * 34; i += 256) ((float*)pl)[i] = 0.f;
  if (tid < 36) wsm[tid / 9][tid % 9] = wpe[((tid / 9) * 256 + co) * 9 + tid % 9];
  __syncthreads();
  for (int i = tid; i < 4 * 1024; i += 256) {
    int p = i >> 10, n = i & 1023;
    int h = n >> 5, ww = n & 31;
    pl[p][(h + 1) * 34 + (ww + 1)] =
        x[(((size_t)b * 256 + co) * 4 + p) * 1024 + n];
  }
  __syncthreads();
  for (int n = tid; n < 1024; n += 256) {
    int h = n >> 5, ww = n & 31;
    float in[4][9];
#pragma unroll
    for (int p = 0; p < 4; ++p)
#pragma unroll
      for (int t = 0; t < 9; ++t)
        in[p][t] = pl[p][(h + t / 3) * 34 + (ww + t % 3)];
#pragma unroll
    for (int q = 0; q < 4; ++q) {
      float acc = bpe[q * 256 + co];
#pragma unroll
      for (int p = 0; p < 4; ++p) {
        int idx = d_IDX[q * 4 + p];
        float s = d_SGN[q * 4 + p];
        float sub = 0.f;
#pragma unroll
        for (int t = 0; t < 9; ++t) sub += in[p][t] * wsm[idx][t];
        acc += s * sub;
      }
      out[(((size_t)b * 256 + co) * 4 + q) * 1024 + n] = acc;
    }
  }
}

// ---------------------------------------------------------------------------
// proj GEMM, swapped orientation: C[m'=(q,o)][n'=bn]. A=weffP rows, B^T=AO rows.
// Epilogue: coalesced fp32 += into out (dwconv already wrote base term).
// ---------------------------------------------------------------------------
__global__ __launch_bounds__(256) void gemm_proj_mfma(
    const u16* __restrict__ AO, const u16* __restrict__ weffP,
    const float* __restrict__ bproj, float* __restrict__ out) {
  __shared__ u16 As[128 * LDK];
  __shared__ u16 Bs[128 * LDK];
  int n0 = blockIdx.x * 128;  // bn
  int m0 = blockIdx.y * 128;  // (q,o)
  int tid = threadIdx.x;
  f32x4 acc[4][4];
#pragma unroll
  for (int i = 0; i < 4; ++i)
#pragma unroll
    for (int j = 0; j < 4; ++j) acc[i][j] = (f32x4){0.f, 0.f, 0.f, 0.f};
  gemm_core(weffP + (size_t)m0 * 1024, AO + (size_t)n0 * 1024, As, Bs, tid, acc);

  int w = tid >> 6, lane = tid & 63, l16 = lane & 15, quad = lane >> 4;
  int mt = (w & 1) * 64, nt = (w >> 1) * 64;
#pragma unroll
  for (int i = 0; i < 4; ++i) {
#pragma unroll
    for (int r = 0; r < 4; ++r) {
      int mrow = m0 + mt + i * 16 + quad * 4 + r;  // (q,o)
      int q = mrow >> 8, o = mrow & 255;
      float bias = bproj[mrow];
#pragma unroll
      for (int j = 0; j < 4; ++j) {
        int n = n0 + nt + j * 16 + l16;  // bn
        int b = n >> 10, npos = n & 1023;
        size_t oidx = (((size_t)b * 256 + o) * 4 + q) * 1024 + npos;
        out[oidx] += acc[i][j][r] + bias;
      }
    }
  }
}

// ---------------------------------------------------------------------------
extern "C" void kernel_launch(void* const* d_in, const int* in_sizes, int n_in,
                              void* d_out, int out_size, void* d_ws,
                              size_t ws_size, hipStream_t stream) {
  const float* x      = (const float*)d_in[0];
  const float* w_qkv  = (const float*)d_in[1];
  const float* b_qkv  = (const float*)d_in[2];
  const float* w_proj = (const float*)d_in[3];
  const float* b_proj = (const float*)d_in[4];
  const float* w_pe   = (const float*)d_in[5];
  const float* b_pe   = (const float*)d_in[6];
  float* out = (float*)d_out;

  u16* ws = (u16*)d_ws;
  u16* weffQ = ws;                                   // 3072*1024
  u16* weffP = weffQ + (size_t)H3 * DIM;             // 1024*1024
  u16* Ax    = weffP + (size_t)DIM * DIM;            // 8192*1024
  u16* Qb    = Ax + (size_t)MM * DIM;                // 8*8*1024*128
  u16* Kb    = Qb + (size_t)BB * NHD * NN * DD;
  u16* Vb    = Kb + (size_t)BB * NHD * NN * DD;
  u16* AO    = Vb + (size_t)BB * NHD * NN * DD;      // 8192*1024
  // total ~74 MB of bf16 scratch

  hipLaunchKernelGGL(prep_weff, dim3(4096), dim3(256), 0, stream,
                     w_qkv, w_proj, weffQ, weffP);
  hipLaunchKernelGGL(prep_x, dim3(8192), dim3(256), 0, stream, x, Ax);
  hipLaunchKernelGGL(gemm_qkv_mfma, dim3(MM / 128, H3 / 128), dim3(256), 0,
                     stream, Ax, weffQ, b_qkv, Qb, Kb, Vb);
  hipLaunchKernelGGL(attn_mfma, dim3(BB * NHD * 16), dim3(256), 0, stream,
                     Qb, Kb, Vb, AO);
  hipLaunchKernelGGL(qdwconv_kernel, dim3(BB * 256), dim3(256), 0, stream,
                     x, w_pe, b_pe, out);
  hipLaunchKernelGGL(gemm_proj_mfma, dim3(MM / 128, DIM / 128), dim3(256), 0,
                     stream, AO, weffP, b_proj, out);
}

// Round 3
// 371.934 us; speedup vs baseline: 6.9899x; 1.0352x over previous
//
#include <hip/hip_runtime.h>
#include <hip/hip_bf16.h>

typedef unsigned short u16;
typedef float f32x4 __attribute__((ext_vector_type(4)));
typedef __bf16 bf16x8 __attribute__((ext_vector_type(8)));
typedef unsigned short su8v __attribute__((ext_vector_type(8)));

#define BB 8
#define NHD 8
#define DD 128
#define NN 1024
#define DIM 1024
#define H3 3072
#define MM 8192
#define KPAD 160   // padded K row (u16): 64-row tile = 20480 B = 5 gll rounds/wave
#define VTS 80     // Vt LDS stride (keys): 128 rows = 20480 B = 5 rounds
#define PTS 72     // P LDS stride
// scale * log2(e), folded into Q weights so softmax is exp2(raw dot)
#define QSC (0.08838834764831845f * 1.4426950408889634f)

__constant__ int   d_IDX[16] = {0,1,2,3, 1,0,3,2, 2,3,0,1, 3,2,1,0};
__constant__ float d_SGN[16] = {1.f,-1.f,-1.f,-1.f, 1.f,1.f,1.f,-1.f,
                                1.f,-1.f,1.f,1.f,  1.f,1.f,-1.f,1.f};

__device__ __forceinline__ f32x4 mfma16(su8v a, su8v b, f32x4 c) {
  return __builtin_amdgcn_mfma_f32_16x16x32_bf16(
      __builtin_bit_cast(bf16x8, a), __builtin_bit_cast(bf16x8, b), c, 0, 0, 0);
}
__device__ __forceinline__ u16 f2b(float f) {  // RNE
  unsigned int u = __builtin_bit_cast(unsigned int, f);
  u += 0x7fffu + ((u >> 16) & 1u);
  return (u16)(u >> 16);
}
typedef const __attribute__((address_space(1))) unsigned int* gas_t;
typedef __attribute__((address_space(3))) unsigned int* las_t;
__device__ __forceinline__ void gll16(const u16* g, u16* l) {
  __builtin_amdgcn_global_load_lds((gas_t)g, (las_t)l, 16, 0, 0);
}

// ---------------------------------------------------------------------------
// prep_weff: effective weights [out_row][in_col] bf16; Q-rows pre-scaled by QSC
// ---------------------------------------------------------------------------
__global__ __launch_bounds__(256) void prep_weff(
    const float* __restrict__ wqkv, const float* __restrict__ wproj,
    u16* __restrict__ weffQ, u16* __restrict__ weffP) {
  int tid = blockIdx.x * 256 + threadIdx.x;
  int stride = gridDim.x * 256;
  for (int i = tid; i < H3 * DIM; i += stride) {
    int row = i >> 10, col = i & 1023;
    int q = row / 768, o = row - q * 768;
    int p = col >> 8, c = col & 255;
    float v = d_SGN[q * 4 + p] * wqkv[(d_IDX[q * 4 + p] * 768 + o) * 256 + c];
    if (o < 256) v *= QSC;  // Q rows
    weffQ[i] = f2b(v);
  }
  for (int i = tid; i < DIM * DIM; i += stride) {
    int row = i >> 10, col = i & 1023;
    int q = row >> 8, o = row & 255;
    int p = col >> 8, c = col & 255;
    weffP[i] = f2b(d_SGN[q * 4 + p] * wproj[(d_IDX[q * 4 + p] * 256 + o) * 256 + c]);
  }
}

// ---------------------------------------------------------------------------
// prep_x: x (B,Cc,4,N) fp32 -> Ax bf16 [8192 (b,n)][1024 (p,c)]
// ---------------------------------------------------------------------------
__global__ __launch_bounds__(256) void prep_x(
    const float* __restrict__ x, u16* __restrict__ Ax) {
  int id = blockIdx.x * 256 + threadIdx.x;
  const float4* xv = (const float4*)x;
  float4 f = xv[id];
  int n4 = id & 255;
  int rem = id >> 8;
  int p = rem & 3, c = (rem >> 2) & 255, b = rem >> 10;
  int col = p * 256 + c;
  size_t rbase = (size_t)(b * 1024 + n4 * 4) * 1024 + col;
  Ax[rbase] = f2b(f.x);
  Ax[rbase + 1024] = f2b(f.y);
  Ax[rbase + 2048] = f2b(f.z);
  Ax[rbase + 3072] = f2b(f.w);
}

// ---------------------------------------------------------------------------
// m97-style GEMM core: 128x128 tile, BK=32, global_load_lds staging.
// LDS tiles [128 rows][32 k] stride 32 (conflict-free for 16x16x32 frags).
// ---------------------------------------------------------------------------
__device__ __forceinline__ void gemm_core2(
    const u16* __restrict__ Ag, const u16* __restrict__ Bg,
    u16* As, u16* Bs, int tid, f32x4 acc[4][4]) {
  int w = tid >> 6, lane = tid & 63, l16 = lane & 15, quad = lane >> 4;
  int mt = (w & 1) * 64, nt = (w >> 1) * 64;
  for (int k0 = 0; k0 < 1024; k0 += 32) {
    __syncthreads();
#pragma unroll
    for (int t = 0; t < 2; ++t) {
      int ci = w * 2 + t;
      int idx = ci * 512 + lane * 8;
      int row = idx >> 5, col = idx & 31;
      gll16(Ag + (size_t)row * 1024 + k0 + col, As + ci * 512);
      gll16(Bg + (size_t)row * 1024 + k0 + col, Bs + ci * 512);
    }
    __syncthreads();
    su8v af[4], bf[4];
#pragma unroll
    for (int i = 0; i < 4; ++i)
      af[i] = *(const su8v*)(As + (mt + i * 16 + l16) * 32 + quad * 8);
#pragma unroll
    for (int j = 0; j < 4; ++j)
      bf[j] = *(const su8v*)(Bs + (nt + j * 16 + l16) * 32 + quad * 8);
#pragma unroll
    for (int i = 0; i < 4; ++i)
#pragma unroll
      for (int j = 0; j < 4; ++j)
        acc[i][j] = mfma16(af[i], bf[j], acc[i][j]);
  }
}

// ---------------------------------------------------------------------------
// QKV GEMM: scatter to Q [bh][n][128], K padded [bh][n][160], V^T [bh][d][n]
// ---------------------------------------------------------------------------
__global__ __launch_bounds__(256) void gemm_qkv_mfma(
    const u16* __restrict__ Ax, const u16* __restrict__ weffQ,
    const float* __restrict__ bqkv,
    u16* __restrict__ Qb, u16* __restrict__ Kb, u16* __restrict__ VbT) {
  __shared__ u16 As[128 * 32];
  __shared__ u16 Bs[128 * 32];
  int m0 = blockIdx.x * 128, n0 = blockIdx.y * 128;
  int tid = threadIdx.x;
  f32x4 acc[4][4];
#pragma unroll
  for (int i = 0; i < 4; ++i)
#pragma unroll
    for (int j = 0; j < 4; ++j) acc[i][j] = (f32x4){0.f, 0.f, 0.f, 0.f};
  gemm_core2(Ax + (size_t)m0 * 1024, weffQ + (size_t)n0 * 1024, As, Bs, tid, acc);

  int w = tid >> 6, lane = tid & 63, l16 = lane & 15, quad = lane >> 4;
  int mt = (w & 1) * 64, nt = (w >> 1) * 64;
#pragma unroll
  for (int j = 0; j < 4; ++j) {
    int n = n0 + nt + j * 16 + l16;
    int q = n / 768, o = n - q * 768;
    int sel = o >> 8, oc = o & 255;
    int ch = q * 256 + oc;
    int head = ch >> 7, d = ch & 127;
    float bias = bqkv[n];
    if (sel == 0) bias *= QSC;
#pragma unroll
    for (int i = 0; i < 4; ++i) {
#pragma unroll
      for (int r = 0; r < 4; ++r) {
        int m = m0 + mt + i * 16 + quad * 4 + r;
        int b = m >> 10, npos = m & 1023;
        int bh = b * NHD + head;
        u16 val = f2b(acc[i][j][r] + bias);
        if (sel == 0)      Qb[((size_t)bh * NN + npos) * DD + d] = val;
        else if (sel == 1) Kb[((size_t)bh * NN + npos) * KPAD + d] = val;
        else               VbT[((size_t)bh * DD + d) * NN + npos] = val;
      }
    }
  }
}

// ---------------------------------------------------------------------------
// Flash attention: 512 blocks (bh x 8), 128 queries/block, 32/wave.
// Q in registers; K,V staged via global_load_lds; exp2 softmax (no max).
// ---------------------------------------------------------------------------
__global__ __launch_bounds__(256) void attn_mfma(
    const u16* __restrict__ Qb, const u16* __restrict__ Kb,
    const u16* __restrict__ VbT, u16* __restrict__ AO) {
  __shared__ u16 Ks[64 * KPAD];    // 20480 B
  __shared__ u16 Vt[128 * VTS];    // 20480 B
  __shared__ u16 Ps[4 * 32 * PTS]; // 18432 B
  int qt = blockIdx.x & 7, bh = blockIdx.x >> 3;
  int n0 = qt * 128;
  int tid = threadIdx.x;
  int w = tid >> 6, lane = tid & 63, l16 = lane & 15, quad = lane >> 4;
  const u16* Qg = Qb + ((size_t)bh * NN + n0) * DD;
  const u16* Kg = Kb + (size_t)bh * NN * KPAD;
  const u16* Vg = VbT + (size_t)bh * DD * NN;
  u16* Pw = Ps + w * 32 * PTS;

  su8v qreg[2][4];
#pragma unroll
  for (int mi = 0; mi < 2; ++mi)
#pragma unroll
    for (int ch = 0; ch < 4; ++ch)
      qreg[mi][ch] = *(const su8v*)(Qg + (size_t)(w * 32 + mi * 16 + l16) * DD +
                                    ch * 32 + quad * 8);

  float ls[2][4] = {{0.f, 0.f, 0.f, 0.f}, {0.f, 0.f, 0.f, 0.f}};
  f32x4 accO[2][8];
#pragma unroll
  for (int mi = 0; mi < 2; ++mi)
#pragma unroll
    for (int dt = 0; dt < 8; ++dt) accO[mi][dt] = (f32x4){0.f, 0.f, 0.f, 0.f};

  for (int kt = 0; kt < 16; ++kt) {
    int c0 = kt * 64;
    __syncthreads();
#pragma unroll
    for (int t = 0; t < 5; ++t) {
      int ci = w * 5 + t;
      int idx = ci * 512 + lane * 8;
      gll16(Kg + (size_t)c0 * KPAD + idx, Ks + ci * 512);
      int dv = idx / VTS, cv = idx - dv * VTS;
      gll16(Vg + (size_t)dv * NN + c0 + cv, Vt + ci * 512);
    }
    __syncthreads();

    // S = Q K^T : 32 q-rows x 64 keys per wave
    f32x4 sacc[2][4];
#pragma unroll
    for (int mi = 0; mi < 2; ++mi)
#pragma unroll
      for (int j = 0; j < 4; ++j) sacc[mi][j] = (f32x4){0.f, 0.f, 0.f, 0.f};
#pragma unroll
    for (int ch = 0; ch < 4; ++ch) {
#pragma unroll
      for (int j = 0; j < 4; ++j) {
        su8v kf = *(const su8v*)(Ks + (j * 16 + l16) * KPAD + ch * 32 + quad * 8);
        sacc[0][j] = mfma16(qreg[0][ch], kf, sacc[0][j]);
        sacc[1][j] = mfma16(qreg[1][ch], kf, sacc[1][j]);
      }
    }

    // p = 2^s (scale*log2e folded into Q); truncate-pack to bf16
#pragma unroll
    for (int mi = 0; mi < 2; ++mi)
#pragma unroll
      for (int j = 0; j < 4; ++j)
#pragma unroll
        for (int r = 0; r < 4; ++r) {
          float p = __builtin_exp2f(sacc[mi][j][r]);
          ls[mi][r] += p;
          Pw[(mi * 16 + quad * 4 + r) * PTS + j * 16 + l16] =
              (u16)(__builtin_bit_cast(unsigned int, p) >> 16);
        }

    // O += P V  (wave-local LDS round trip; DS pipe is in-order per wave)
#pragma unroll
    for (int ch = 0; ch < 2; ++ch) {
      su8v pf0 = *(const su8v*)(Pw + l16 * PTS + ch * 32 + quad * 8);
      su8v pf1 = *(const su8v*)(Pw + (16 + l16) * PTS + ch * 32 + quad * 8);
#pragma unroll
      for (int dt = 0; dt < 8; ++dt) {
        su8v vf = *(const su8v*)(Vt + (dt * 16 + l16) * VTS + ch * 32 + quad * 8);
        accO[0][dt] = mfma16(pf0, vf, accO[0][dt]);
        accO[1][dt] = mfma16(pf1, vf, accO[1][dt]);
      }
    }
  }

  // row sums across the 16 lanes sharing each row
#pragma unroll
  for (int mi = 0; mi < 2; ++mi)
#pragma unroll
    for (int r = 0; r < 4; ++r) {
      float s = ls[mi][r];
#pragma unroll
      for (int off = 1; off < 16; off <<= 1) s += __shfl_xor(s, off, 64);
      ls[mi][r] = s;
    }

  int b = bh >> 3, head = bh & 7;
#pragma unroll
  for (int mi = 0; mi < 2; ++mi)
#pragma unroll
    for (int r = 0; r < 4; ++r) {
      float inv = 1.0f / ls[mi][r];
      size_t rowbase =
          (size_t)(b * 1024 + n0 + w * 32 + mi * 16 + quad * 4 + r) * 1024 +
          head * 128;
#pragma unroll
      for (int dt = 0; dt < 8; ++dt)
        AO[rowbase + dt * 16 + l16] = f2b(accO[mi][dt][r] * inv);
    }
}

// ---------------------------------------------------------------------------
// quaternion depthwise 3x3 conv (fp32) — writes base term of out
// ---------------------------------------------------------------------------
__global__ __launch_bounds__(256) void qdwconv_kernel(
    const float* __restrict__ x, const float* __restrict__ wpe,
    const float* __restrict__ bpe, float* __restrict__ out) {
  int blk = blockIdx.x;
  int co = blk & 255;
  int b = blk >> 8;
  __shared__ float pl[4][34 * 34];
  __shared__ float wsm[4][9];
  int tid = threadIdx.x;
  for (int i = tid; i < 4 * 34 * 34; i += 256) ((float*)pl)[i] = 0.f;
  if (tid < 36) wsm[tid / 9][tid % 9] = wpe[((tid / 9) * 256 + co) * 9 + tid % 9];
  __syncthreads();
  for (int i = tid; i < 4 * 1024; i += 256) {
    int p = i >> 10, n = i & 1023;
    int h = n >> 5, ww = n & 31;
    pl[p][(h + 1) * 34 + (ww + 1)] =
        x[(((size_t)b * 256 + co) * 4 + p) * 1024 + n];
  }
  __syncthreads();
  for (int n = tid; n < 1024; n += 256) {
    int h = n >> 5, ww = n & 31;
    float in[4][9];
#pragma unroll
    for (int p = 0; p < 4; ++p)
#pragma unroll
      for (int t = 0; t < 9; ++t)
        in[p][t] = pl[p][(h + t / 3) * 34 + (ww + t % 3)];
#pragma unroll
    for (int q = 0; q < 4; ++q) {
      float acc = bpe[q * 256 + co];
#pragma unroll
      for (int p = 0; p < 4; ++p) {
        int idx = d_IDX[q * 4 + p];
        float s = d_SGN[q * 4 + p];
        float sub = 0.f;
#pragma unroll
        for (int t = 0; t < 9; ++t) sub += in[p][t] * wsm[idx][t];
        acc += s * sub;
      }
      out[(((size_t)b * 256 + co) * 4 + q) * 1024 + n] = acc;
    }
  }
}

// ---------------------------------------------------------------------------
// proj GEMM (swapped orientation): C[m=(q,o)][n=bn]; epilogue += into out
// ---------------------------------------------------------------------------
__global__ __launch_bounds__(256) void gemm_proj_mfma(
    const u16* __restrict__ AO, const u16* __restrict__ weffP,
    const float* __restrict__ bproj, float* __restrict__ out) {
  __shared__ u16 As[128 * 32];
  __shared__ u16 Bs[128 * 32];
  int n0 = blockIdx.x * 128;  // bn
  int m0 = blockIdx.y * 128;  // (q,o)
  int tid = threadIdx.x;
  f32x4 acc[4][4];
#pragma unroll
  for (int i = 0; i < 4; ++i)
#pragma unroll
    for (int j = 0; j < 4; ++j) acc[i][j] = (f32x4){0.f, 0.f, 0.f, 0.f};
  gemm_core2(weffP + (size_t)m0 * 1024, AO + (size_t)n0 * 1024, As, Bs, tid, acc);

  int w = tid >> 6, lane = tid & 63, l16 = lane & 15, quad = lane >> 4;
  int mt = (w & 1) * 64, nt = (w >> 1) * 64;
#pragma unroll
  for (int i = 0; i < 4; ++i) {
#pragma unroll
    for (int r = 0; r < 4; ++r) {
      int mrow = m0 + mt + i * 16 + quad * 4 + r;
      int q = mrow >> 8, o = mrow & 255;
      float bias = bproj[mrow];
#pragma unroll
      for (int j = 0; j < 4; ++j) {
        int n = n0 + nt + j * 16 + l16;
        int b = n >> 10, npos = n & 1023;
        size_t oidx = (((size_t)b * 256 + o) * 4 + q) * 1024 + npos;
        out[oidx] += acc[i][j][r] + bias;
      }
    }
  }
}

// ---------------------------------------------------------------------------
extern "C" void kernel_launch(void* const* d_in, const int* in_sizes, int n_in,
                              void* d_out, int out_size, void* d_ws,
                              size_t ws_size, hipStream_t stream) {
  const float* x      = (const float*)d_in[0];
  const float* w_qkv  = (const float*)d_in[1];
  const float* b_qkv  = (const float*)d_in[2];
  const float* w_proj = (const float*)d_in[3];
  const float* b_proj = (const float*)d_in[4];
  const float* w_pe   = (const float*)d_in[5];
  const float* b_pe   = (const float*)d_in[6];
  float* out = (float*)d_out;

  u16* ws = (u16*)d_ws;
  u16* weffQ = ws;                                   // 3072*1024
  u16* weffP = weffQ + (size_t)H3 * DIM;             // 1024*1024
  u16* Ax    = weffP + (size_t)DIM * DIM;            // 8192*1024
  u16* Qb    = Ax + (size_t)MM * DIM;                // 64*1024*128
  u16* Kb    = Qb + (size_t)BB * NHD * NN * DD;      // 64*1024*160
  u16* VbT   = Kb + (size_t)BB * NHD * NN * KPAD;    // 64*128*1024
  u16* AO    = VbT + (size_t)BB * NHD * DD * NN;     // 8192*1024
  // total ~96.5 MB bf16 scratch

  hipLaunchKernelGGL(prep_weff, dim3(4096), dim3(256), 0, stream,
                     w_qkv, w_proj, weffQ, weffP);
  hipLaunchKernelGGL(prep_x, dim3(8192), dim3(256), 0, stream, x, Ax);
  hipLaunchKernelGGL(gemm_qkv_mfma, dim3(MM / 128, H3 / 128), dim3(256), 0,
                     stream, Ax, weffQ, b_qkv, Qb, Kb, VbT);
  hipLaunchKernelGGL(attn_mfma, dim3(BB * NHD * 8), dim3(256), 0, stream,
                     Qb, Kb, VbT, AO);
  hipLaunchKernelGGL(qdwconv_kernel, dim3(BB * 256), dim3(256), 0, stream,
                     x, w_pe, b_pe, out);
  hipLaunchKernelGGL(gemm_proj_mfma, dim3(MM / 128, DIM / 128), dim3(256), 0,
                     stream, AO, weffP, b_proj, out);
}